// Round 4
// baseline (194.670 us; speedup 1.0000x reference)
//
#include <hip/hip_runtime.h>

#define NGRID 512
#define NV (NGRID * NGRID)          // 262144
#define NB 4
#define NVIEWS 4
#define FEPS 1e-6f
#define TR 2                        // owned rows per block (loss kernel)
#define LDS_ROWS (TR + 2)           // + top/bottom halo
#define ROWF (NGRID * 3)            // 1536 floats per row
#define LDSF (LDS_ROWS * ROWF)      // 6144 floats = 24 KB

typedef float fvec4 __attribute__((ext_vector_type(4)));

static constexpr size_t NVF3 = (size_t)NV * 3;                      // 786432
static constexpr size_t BLK4 = NVF3 / 4;                            // 196608
static constexpr size_t VERTS_FLOATS = (size_t)NVIEWS * NB * NVF3;  // 12,582,912
static constexpr size_t LAP_OFF = 2 * VERTS_FLOATS;
static constexpr size_t FLAT_OFF = LAP_OFF + 1;

__device__ __forceinline__ float frcp(float x)  { return __builtin_amdgcn_rcpf(x); }
__device__ __forceinline__ float fsqrt_(float x){ return __builtin_amdgcn_sqrtf(x); }

// ---------------------------------------------------------------------------
// Transform: v = sigma*(sgn - c) + c, sigma = s / (s + (1-s)*exp(-d))
__device__ __forceinline__ float xform(float tvl, float d, float c) {
    const float s = fabsf(tvl);
    const float sgn = (tvl > 0.0f) ? 1.0f : -1.0f;
    const float e = __expf(-d);
    const float sigma = s * frcp(fmaf(1.0f - s, e, s));
    return fmaf(sigma, sgn - c, c);
}

// ---------------------------------------------------------------------------
// Kernel A: pure streaming. Recomputes transform per chunk, writes
// verts x4 views + tex x4 views non-temporally. No LDS, no barriers.
// Also zero-inits the two loss accumulators (block (0,0)).
__global__ __launch_bounds__(256) void transform_store_kernel(
    const float* __restrict__ disp, const float* __restrict__ center,
    const float* __restrict__ tex, const float* __restrict__ tv,
    float* __restrict__ out)
{
    const int tid = threadIdx.x;
    const int b = blockIdx.y;

    if (blockIdx.x == 0 && b == 0 && tid == 0) {
        out[LAP_OFF] = 0.0f;
        out[FLAT_OFF] = 0.0f;
    }

    const float c0 = tanhf(center[b * 3 + 0]);
    const float c1 = tanhf(center[b * 3 + 1]);
    const float c2 = tanhf(center[b * 3 + 2]);
    const float carr[3] = {c0, c1, c2};

    const fvec4* __restrict__ tv4 = (const fvec4*)tv;
    const fvec4* __restrict__ d4p = (const fvec4*)(disp + (size_t)b * NVF3);
    const fvec4* __restrict__ t4p = (const fvec4*)(tex + (size_t)b * NVF3);
    fvec4* __restrict__ out4 = (fvec4*)out;

    for (int g4 = blockIdx.x * 256 + tid; g4 < (int)BLK4; g4 += gridDim.x * 256) {
        const fvec4 t = tv4[g4];
        const fvec4 d = d4p[g4];
        const fvec4 tx = __builtin_nontemporal_load(&t4p[g4]);
        fvec4 vr;
        int comp = g4 % 3;   // (4*g4) % 3 == g4 % 3
#pragma unroll
        for (int l = 0; l < 4; ++l) {
            vr[l] = xform(t[l], d[l], carr[comp]);
            comp = (comp == 2) ? 0 : comp + 1;
        }
#pragma unroll
        for (int view = 0; view < NVIEWS; ++view) {
            const size_t base = (size_t)(b * NVIEWS + view) * BLK4;
            __builtin_nontemporal_store(vr, &out4[base + g4]);
            __builtin_nontemporal_store(tx, &out4[(VERTS_FLOATS / 4) + base + g4]);
        }
    }
}

// ---------------------------------------------------------------------------
__device__ __forceinline__ float3 ldsP(const float* __restrict__ vs, int lr, int c) {
    const int o = lr * ROWF + c * 3;
    return make_float3(vs[o], vs[o + 1], vs[o + 2]);
}

__device__ __forceinline__ float edge_val(float3 p0, float3 p1, float3 p2, float3 p3) {
    const float a1x = p1.x - p0.x, a1y = p1.y - p0.y, a1z = p1.z - p0.z;
    const float a1l2 = a1x * a1x + a1y * a1y + a1z * a1z;
    const float a1l1 = fsqrt_(a1l2 + FEPS);
    const float inv_a1l2 = frcp(a1l2 + FEPS);

    const float b1x = p2.x - p0.x, b1y = p2.y - p0.y, b1z = p2.z - p0.z;
    const float b1l2 = b1x * b1x + b1y * b1y + b1z * b1z;
    const float b1l1 = fsqrt_(b1l2 + FEPS);
    const float ab1 = a1x * b1x + a1y * b1y + a1z * b1z;
    const float cos1 = ab1 * frcp(a1l1 * b1l1 + FEPS);
    const float sin1 = fsqrt_(1.0f - cos1 * cos1 + FEPS);
    const float f1 = ab1 * inv_a1l2;
    const float cb1x = b1x - a1x * f1, cb1y = b1y - a1y * f1, cb1z = b1z - a1z * f1;
    const float l1 = b1l1 * sin1;

    const float b2x = p3.x - p0.x, b2y = p3.y - p0.y, b2z = p3.z - p0.z;
    const float b2l2 = b2x * b2x + b2y * b2y + b2z * b2z;
    const float b2l1 = fsqrt_(b2l2 + FEPS);
    const float ab2 = a1x * b2x + a1y * b2y + a1z * b2z;
    const float cos2 = ab2 * frcp(a1l1 * b2l1 + FEPS);
    const float sin2 = fsqrt_(1.0f - cos2 * cos2 + FEPS);
    const float f2 = ab2 * inv_a1l2;
    const float cb2x = b2x - a1x * f2, cb2y = b2y - a1y * f2, cb2z = b2z - a1z * f2;
    const float l2 = b2l1 * sin2;

    const float cosd = (cb1x * cb2x + cb1y * cb2y + cb1z * cb2z) * frcp(l1 * l2 + FEPS);
    const float t = cosd + 1.0f;
    return t * t;
}

// ---------------------------------------------------------------------------
// Kernel B: losses only. One block = (2-row tile, batch). Stages v (with
// 1-row halo) in packed-float3 LDS via recompute, computes lap + flat
// losses for owned rows from LDS. (Round-1-verified code, store phase removed.)
__global__ __launch_bounds__(256) void loss_kernel(
    const float* __restrict__ disp, const float* __restrict__ center,
    const float* __restrict__ tv, float* __restrict__ out)
{
    __shared__ float vs[LDSF];
    const int tid = threadIdx.x;
    const int b = blockIdx.y;
    const int R0 = blockIdx.x * TR;

    const float c0 = tanhf(center[b * 3 + 0]);
    const float c1 = tanhf(center[b * 3 + 1]);
    const float c2 = tanhf(center[b * 3 + 2]);
    const float carr[3] = {c0, c1, c2};

    // ---- Stage v for rows [R0-1, R0+TR] into LDS (float4 vectorized) ----
    {
        const fvec4* __restrict__ tv4 = (const fvec4*)tv;
        const fvec4* __restrict__ d4p = (const fvec4*)(disp + (size_t)b * NVF3);
        fvec4* __restrict__ vs4 = (fvec4*)vs;
        const int start4 = (R0 - 1) * (ROWF / 4);          // may be negative (tile 0)
#pragma unroll
        for (int ss = 0; ss < LDSF / 4 / 256; ++ss) {
            const int ff4 = ss * 256 + tid;
            const int g4 = start4 + ff4;
            if (g4 < 0 || g4 >= (int)(NVF3 / 4)) continue;
            const fvec4 t = tv4[g4];
            const fvec4 d = d4p[g4];
            fvec4 vr;
            int comp = ff4 % 3;   // (4*g4)%3 == g4%3 == ff4%3 (start4 % 3 == 0)
#pragma unroll
            for (int l = 0; l < 4; ++l) {
                vr[l] = xform(t[l], d[l], carr[comp]);
                comp = (comp == 2) ? 0 : comp + 1;
            }
            vs4[ff4] = vr;
        }
    }
    __syncthreads();

    // ---- Lap + flat losses for owned rows (reads LDS only) ----
    float lap_sum = 0.0f, flat_sum = 0.0f;
#pragma unroll 1
    for (int it = 0; it < TR * NGRID / 256; ++it) {
        const int idx = it * 256 + tid;
        const int r_off = idx >> 9;            // 0..TR-1
        const int c = idx & (NGRID - 1);
        const int gr = R0 + r_off;             // global row
        const int lr = r_off + 1;              // LDS row

        const float3 pc = ldsP(vs, lr, c);

        // Laplacian
        {
            float sx = 0.f, sy = 0.f, sz = 0.f;
            int deg = 0;
            if (gr > 0)               { float3 p = ldsP(vs, lr - 1, c);     sx += p.x; sy += p.y; sz += p.z; deg++; }
            if (gr < NGRID - 1)       { float3 p = ldsP(vs, lr + 1, c);     sx += p.x; sy += p.y; sz += p.z; deg++; }
            if (c > 0)                { float3 p = ldsP(vs, lr, c - 1);     sx += p.x; sy += p.y; sz += p.z; deg++; }
            if (c < NGRID - 1)        { float3 p = ldsP(vs, lr, c + 1);     sx += p.x; sy += p.y; sz += p.z; deg++; }
            if (gr > 0 && c < NGRID - 1)      { float3 p = ldsP(vs, lr - 1, c + 1); sx += p.x; sy += p.y; sz += p.z; deg++; }
            if (gr < NGRID - 1 && c > 0)      { float3 p = ldsP(vs, lr + 1, c - 1); sx += p.x; sy += p.y; sz += p.z; deg++; }
            const float id = frcp((float)deg);
            const float lx = pc.x - sx * id;
            const float ly = pc.y - sy * id;
            const float lz = pc.z - sz * id;
            lap_sum += lx * lx + ly * ly + lz * lz;
        }

        // Flat loss: up to 3 structural edges anchored at (gr, c)
        if (gr < NGRID - 1 && c < NGRID - 1) {
            flat_sum += edge_val(ldsP(vs, lr, c + 1), ldsP(vs, lr + 1, c),
                                 pc,                  ldsP(vs, lr + 1, c + 1));
        }
        if (gr >= 1 && gr < NGRID - 1 && c < NGRID - 1) {
            flat_sum += edge_val(pc, ldsP(vs, lr, c + 1),
                                 ldsP(vs, lr + 1, c), ldsP(vs, lr - 1, c + 1));
        }
        if (gr < NGRID - 1 && c >= 1 && c < NGRID - 1) {
            flat_sum += edge_val(pc, ldsP(vs, lr + 1, c),
                                 ldsP(vs, lr, c + 1), ldsP(vs, lr + 1, c - 1));
        }
    }

    // ---- Block reduction (two values), one atomic pair per block ----
#pragma unroll
    for (int off = 32; off > 0; off >>= 1) {
        lap_sum  += __shfl_down(lap_sum, off, 64);
        flat_sum += __shfl_down(flat_sum, off, 64);
    }
    __shared__ float red[8];
    const int lane = tid & 63;
    const int wid = tid >> 6;
    if (lane == 0) { red[wid] = lap_sum; red[4 + wid] = flat_sum; }
    __syncthreads();
    if (tid == 0) {
        const float ls = red[0] + red[1] + red[2] + red[3];
        const float fs = red[4] + red[5] + red[6] + red[7];
        atomicAdd(&out[LAP_OFF],  ls * (1.0f / NB));
        atomicAdd(&out[FLAT_OFF], fs * (1.0f / NB));
    }
}

// ---------------------------------------------------------------------------
extern "C" void kernel_launch(void* const* d_in, const int* in_sizes, int n_in,
                              void* d_out, int out_size, void* d_ws, size_t ws_size,
                              hipStream_t stream)
{
    const float* disp   = (const float*)d_in[0];
    const float* center = (const float*)d_in[1];
    const float* tex    = (const float*)d_in[2];
    const float* tv     = (const float*)d_in[3];
    float* out = (float*)d_out;

    // A: streaming transform + 8-way view stores (also inits loss slots).
    transform_store_kernel<<<dim3(512, NB), 256, 0, stream>>>(disp, center, tex, tv, out);
    // B: losses (atomics ordered after A by stream order).
    loss_kernel<<<dim3(NGRID / TR, NB), 256, 0, stream>>>(disp, center, tv, out);
}

// Round 5
// 177.318 us; speedup vs baseline: 1.0979x; 1.0979x over previous
//
#include <hip/hip_runtime.h>

#define NGRID 512
#define NV (NGRID * NGRID)          // 262144
#define NB 4
#define NVIEWS 4
#define FEPS 1e-6f
#define TR 2                        // owned rows per block
#define LDS_ROWS (TR + 2)           // + top/bottom halo
#define ROWF (NGRID * 3)            // 1536 floats per row
#define LDSF (LDS_ROWS * ROWF)      // 6144 floats = 24 KB

typedef float fvec4 __attribute__((ext_vector_type(4)));

static constexpr size_t NVF3 = (size_t)NV * 3;                      // 786432
static constexpr size_t VERTS_FLOATS = (size_t)NVIEWS * NB * NVF3;  // 12,582,912
static constexpr size_t LAP_OFF = 2 * VERTS_FLOATS;
static constexpr size_t FLAT_OFF = LAP_OFF + 1;

__device__ __forceinline__ float frcp(float x)  { return __builtin_amdgcn_rcpf(x); }
__device__ __forceinline__ float fsqrt_(float x){ return __builtin_amdgcn_sqrtf(x); }

// ---------------------------------------------------------------------------
__global__ void init_losses(float* __restrict__ out) {
    if (threadIdx.x == 0) {
        out[LAP_OFF] = 0.0f;
        out[FLAT_OFF] = 0.0f;
    }
}

// ---------------------------------------------------------------------------
__device__ __forceinline__ float3 ldsP(const float* __restrict__ vs, int lr, int c) {
    const int o = lr * ROWF + c * 3;
    return make_float3(vs[o], vs[o + 1], vs[o + 2]);
}

__device__ __forceinline__ float edge_val(float3 p0, float3 p1, float3 p2, float3 p3) {
    const float a1x = p1.x - p0.x, a1y = p1.y - p0.y, a1z = p1.z - p0.z;
    const float a1l2 = a1x * a1x + a1y * a1y + a1z * a1z;
    const float a1l1 = fsqrt_(a1l2 + FEPS);
    const float inv_a1l2 = frcp(a1l2 + FEPS);

    const float b1x = p2.x - p0.x, b1y = p2.y - p0.y, b1z = p2.z - p0.z;
    const float b1l2 = b1x * b1x + b1y * b1y + b1z * b1z;
    const float b1l1 = fsqrt_(b1l2 + FEPS);
    const float ab1 = a1x * b1x + a1y * b1y + a1z * b1z;
    const float cos1 = ab1 * frcp(a1l1 * b1l1 + FEPS);
    const float sin1 = fsqrt_(1.0f - cos1 * cos1 + FEPS);
    const float f1 = ab1 * inv_a1l2;
    const float cb1x = b1x - a1x * f1, cb1y = b1y - a1y * f1, cb1z = b1z - a1z * f1;
    const float l1 = b1l1 * sin1;

    const float b2x = p3.x - p0.x, b2y = p3.y - p0.y, b2z = p3.z - p0.z;
    const float b2l2 = b2x * b2x + b2y * b2y + b2z * b2z;
    const float b2l1 = fsqrt_(b2l2 + FEPS);
    const float ab2 = a1x * b2x + a1y * b2y + a1z * b2z;
    const float cos2 = ab2 * frcp(a1l1 * b2l1 + FEPS);
    const float sin2 = fsqrt_(1.0f - cos2 * cos2 + FEPS);
    const float f2 = ab2 * inv_a1l2;
    const float cb2x = b2x - a1x * f2, cb2y = b2y - a1y * f2, cb2z = b2z - a1z * f2;
    const float l2 = b2l1 * sin2;

    const float cosd = (cb1x * cb2x + cb1y * cb2y + cb1z * cb2z) * frcp(l1 * l2 + FEPS);
    const float t = cosd + 1.0f;
    return t * t;
}

// ---------------------------------------------------------------------------
// Mega-kernel: one block = (2-row tile, batch). Stages v (with 1-row halo)
// in LDS via recompute, writes verts x4 views + tex x4 views (PLAIN stores:
// let L2/L3 absorb them instead of nt-bypassing to HBM, which contends with
// the poison-fill drain), computes lap + flat losses for owned rows from LDS.
__global__ __launch_bounds__(256) void mesh_fused_kernel(
    const float* __restrict__ disp, const float* __restrict__ center,
    const float* __restrict__ tex, const float* __restrict__ tv,
    float* __restrict__ out)
{
    __shared__ float vs[LDSF];
    const int tid = threadIdx.x;
    const int b = blockIdx.y;
    const int R0 = blockIdx.x * TR;

    const float c0 = tanhf(center[b * 3 + 0]);
    const float c1 = tanhf(center[b * 3 + 1]);
    const float c2 = tanhf(center[b * 3 + 2]);
    const float carr[3] = {c0, c1, c2};

    // ---- Stage v for rows [R0-1, R0+TR] into LDS (float4 vectorized) ----
    {
        const fvec4* __restrict__ tv4 = (const fvec4*)tv;
        const fvec4* __restrict__ d4p = (const fvec4*)(disp + (size_t)b * NVF3);
        fvec4* __restrict__ vs4 = (fvec4*)vs;
        const int start4 = (R0 - 1) * (ROWF / 4);          // may be negative (tile 0)
#pragma unroll
        for (int ss = 0; ss < LDSF / 4 / 256; ++ss) {
            const int ff4 = ss * 256 + tid;
            const int g4 = start4 + ff4;
            if (g4 < 0 || g4 >= (int)(NVF3 / 4)) continue;
            const fvec4 t = tv4[g4];
            const fvec4 d = d4p[g4];
            fvec4 vr;
            int comp = ff4 % 3;   // (4*g4)%3 == g4%3 == ff4%3 (start4 % 3 == 0)
#pragma unroll
            for (int l = 0; l < 4; ++l) {
                const float tvl = t[l];
                const float s = fabsf(tvl);
                const float sgn = (tvl > 0.0f) ? 1.0f : -1.0f;
                // sigma = sigmoid(log(s/(1-s)) + d) = s / (s + (1-s)*exp(-d))
                const float e = __expf(-d[l]);
                const float sigma = s * frcp(fmaf(1.0f - s, e, s));
                // v = relu(v0)(1-c) - relu(-v0)(1+c) + c  ==  sigma*(sgn - c) + c
                const float c = carr[comp];
                vr[l] = fmaf(sigma, sgn - c, c);
                comp = (comp == 2) ? 0 : comp + 1;
            }
            vs4[ff4] = vr;
        }
    }
    __syncthreads();

    // ---- Write verts x4 views + tex x4 views for owned rows (plain stores) ----
    {
        const fvec4* __restrict__ vs4 = (const fvec4*)vs;
        const fvec4* __restrict__ t4p = (const fvec4*)(tex + (size_t)b * NVF3);
        fvec4* __restrict__ out4 = (fvec4*)out;
        const size_t blk4 = NVF3 / 4;                       // 196608
        const int tile_base4 = R0 * (ROWF / 4);             // float4 offset of row R0
#pragma unroll
        for (int qq = 0; qq < TR * ROWF / 4 / 256; ++qq) {
            const int q = qq * 256 + tid;
            const fvec4 vo = vs4[ROWF / 4 + q];             // skip halo row
            const fvec4 tx = t4p[tile_base4 + q];
            const size_t pos4 = (size_t)tile_base4 + q;
#pragma unroll
            for (int view = 0; view < NVIEWS; ++view) {
                const size_t base = (size_t)(b * NVIEWS + view) * blk4;
                out4[base + pos4] = vo;
                out4[(VERTS_FLOATS / 4) + base + pos4] = tx;
            }
        }
    }

    // ---- Lap + flat losses for owned rows (reads LDS only) ----
    float lap_sum = 0.0f, flat_sum = 0.0f;
#pragma unroll 1
    for (int it = 0; it < TR * NGRID / 256; ++it) {
        const int idx = it * 256 + tid;
        const int r_off = idx >> 9;            // 0..TR-1
        const int c = idx & (NGRID - 1);
        const int gr = R0 + r_off;             // global row
        const int lr = r_off + 1;              // LDS row

        const float3 pc = ldsP(vs, lr, c);

        // Laplacian
        {
            float sx = 0.f, sy = 0.f, sz = 0.f;
            int deg = 0;
            if (gr > 0)               { float3 p = ldsP(vs, lr - 1, c);     sx += p.x; sy += p.y; sz += p.z; deg++; }
            if (gr < NGRID - 1)       { float3 p = ldsP(vs, lr + 1, c);     sx += p.x; sy += p.y; sz += p.z; deg++; }
            if (c > 0)                { float3 p = ldsP(vs, lr, c - 1);     sx += p.x; sy += p.y; sz += p.z; deg++; }
            if (c < NGRID - 1)        { float3 p = ldsP(vs, lr, c + 1);     sx += p.x; sy += p.y; sz += p.z; deg++; }
            if (gr > 0 && c < NGRID - 1)      { float3 p = ldsP(vs, lr - 1, c + 1); sx += p.x; sy += p.y; sz += p.z; deg++; }
            if (gr < NGRID - 1 && c > 0)      { float3 p = ldsP(vs, lr + 1, c - 1); sx += p.x; sy += p.y; sz += p.z; deg++; }
            const float id = frcp((float)deg);
            const float lx = pc.x - sx * id;
            const float ly = pc.y - sy * id;
            const float lz = pc.z - sz * id;
            lap_sum += lx * lx + ly * ly + lz * lz;
        }

        // Flat loss: up to 3 structural edges anchored at (gr, c)
        if (gr < NGRID - 1 && c < NGRID - 1) {
            flat_sum += edge_val(ldsP(vs, lr, c + 1), ldsP(vs, lr + 1, c),
                                 pc,                  ldsP(vs, lr + 1, c + 1));
        }
        if (gr >= 1 && gr < NGRID - 1 && c < NGRID - 1) {
            flat_sum += edge_val(pc, ldsP(vs, lr, c + 1),
                                 ldsP(vs, lr + 1, c), ldsP(vs, lr - 1, c + 1));
        }
        if (gr < NGRID - 1 && c >= 1 && c < NGRID - 1) {
            flat_sum += edge_val(pc, ldsP(vs, lr + 1, c),
                                 ldsP(vs, lr, c + 1), ldsP(vs, lr + 1, c - 1));
        }
    }

    // ---- Block reduction (two values), one atomic pair per block ----
#pragma unroll
    for (int off = 32; off > 0; off >>= 1) {
        lap_sum  += __shfl_down(lap_sum, off, 64);
        flat_sum += __shfl_down(flat_sum, off, 64);
    }
    __shared__ float red[8];
    const int lane = tid & 63;
    const int wid = tid >> 6;
    if (lane == 0) { red[wid] = lap_sum; red[4 + wid] = flat_sum; }
    __syncthreads();
    if (tid == 0) {
        const float ls = red[0] + red[1] + red[2] + red[3];
        const float fs = red[4] + red[5] + red[6] + red[7];
        atomicAdd(&out[LAP_OFF],  ls * (1.0f / NB));
        atomicAdd(&out[FLAT_OFF], fs * (1.0f / NB));
    }
}

// ---------------------------------------------------------------------------
extern "C" void kernel_launch(void* const* d_in, const int* in_sizes, int n_in,
                              void* d_out, int out_size, void* d_ws, size_t ws_size,
                              hipStream_t stream)
{
    const float* disp   = (const float*)d_in[0];
    const float* center = (const float*)d_in[1];
    const float* tex    = (const float*)d_in[2];
    const float* tv     = (const float*)d_in[3];
    float* out = (float*)d_out;

    init_losses<<<1, 64, 0, stream>>>(out);
    mesh_fused_kernel<<<dim3(NGRID / TR, NB), 256, 0, stream>>>(disp, center, tex, tv, out);
}